// Round 1
// baseline (147.640 us; speedup 1.0000x reference)
//
#include <hip/hip_runtime.h>

typedef _Float16 half8 __attribute__((ext_vector_type(8)));
typedef float f32x4 __attribute__((ext_vector_type(4)));

#define MFMA_F16(A, B, C) __builtin_amdgcn_mfma_f32_16x16x32_f16(A, B, C, 0, 0, 0)

// sizes
#define NN 200000
#define IND 128
#define HID 64
#define WLEN 16
#define NWALK 16384
#define NG 1024

// ---------------- Kernel 1: encoder  x_enc = fp16(x @ Wenc^T + benc) ----------------
__global__ __launch_bounds__(256) void k_enc(const float* __restrict__ x,
                                             const float* __restrict__ Wenc,
                                             const float* __restrict__ benc,
                                             _Float16* __restrict__ xenc) {
  const int lane = threadIdx.x & 63;
  const int wv = threadIdx.x >> 6;
  const int r = lane & 15, g = lane >> 4;
  const int row0 = blockIdx.x * 64 + wv * 16;

  // B fragments: B[k][j] = Wenc[j][k], j = jt*16 + r, k = kt*32 + g*8 + e
  half8 B[4][4];
#pragma unroll
  for (int jt = 0; jt < 4; ++jt)
#pragma unroll
    for (int kt = 0; kt < 4; ++kt) {
      const float* p = Wenc + (jt * 16 + r) * 128 + kt * 32 + g * 8;
      half8 b;
#pragma unroll
      for (int e = 0; e < 8; ++e) b[e] = (_Float16)p[e];
      B[jt][kt] = b;
    }

  f32x4 acc[4];
#pragma unroll
  for (int jt = 0; jt < 4; ++jt) {
    float bb = benc[jt * 16 + r];
    acc[jt] = (f32x4){bb, bb, bb, bb};
  }

#pragma unroll
  for (int kt = 0; kt < 4; ++kt) {
    const float* p = x + (size_t)(row0 + r) * 128 + kt * 32 + g * 8;
    half8 a;
#pragma unroll
    for (int e = 0; e < 8; ++e) a[e] = (_Float16)p[e];
#pragma unroll
    for (int jt = 0; jt < 4; ++jt)
      acc[jt] = MFMA_F16(a, B[jt][kt], acc[jt]);
  }

  // C/D layout: col = lane&15, row = (lane>>4)*4 + reg  (m89-verified)
#pragma unroll
  for (int jt = 0; jt < 4; ++jt)
#pragma unroll
    for (int rr = 0; rr < 4; ++rr) {
      int row = row0 + g * 4 + rr;
      xenc[(size_t)row * 64 + jt * 16 + r] = (_Float16)acc[jt][rr];
    }
}

// ---------------- Kernel 2: GRU over walks + per-graph mean pooling ----------------
// 1 wave = 1 graph = 16 walks. grid 256 x 256thr.
__global__ __launch_bounds__(256) void k_gru(const _Float16* __restrict__ xenc,
                                             const int* __restrict__ walks,
                                             const float* __restrict__ Wih,
                                             const float* __restrict__ Whh,
                                             const float* __restrict__ bih,
                                             const float* __restrict__ bhh,
                                             float* __restrict__ genc) {
  __shared__ _Float16 wih_lds[24 * 64 * 8];  // frag-packed fp16 W_ih (24 KB)
  __shared__ _Float16 h_lds[4][16 * 64];     // per-wave h transpose buffer (8 KB)
  __shared__ int ids[4][256];                // per-wave walk node ids, transposed (4 KB)

  const int tid = threadIdx.x;
  const int lane = tid & 63, wv = tid >> 6;
  const int r = lane & 15, g = lane >> 4;

  // stage W_ih -> frag-packed fp16 LDS:
  // element (j,k) -> tile (j/16)*2 + k/32, lane ((k%32)/8)*16 + j%16, elem k%8
  for (int idx = tid; idx < 192 * 64; idx += 256) {
    int j = idx >> 6, k = idx & 63;
    int tile = (j >> 4) * 2 + (k >> 5);
    int ln = ((k >> 3) & 3) * 16 + (j & 15);
    wih_lds[(tile * 64 + ln) * 8 + (k & 7)] = (_Float16)Wih[idx];
  }

  // W_hh fragments live in registers (reused 16 steps): 24 frags = 96 VGPR
  half8 Bhh[12][2];
#pragma unroll
  for (int jt = 0; jt < 12; ++jt)
#pragma unroll
    for (int kt = 0; kt < 2; ++kt) {
      const float* p = Whh + (jt * 16 + r) * 64 + kt * 32 + g * 8;
      half8 b;
#pragma unroll
      for (int e = 0; e < 8; ++e) b[e] = (_Float16)p[e];
      Bhh[jt][kt] = b;
    }

  // per-lane biases (indexed by output col = jt*16 + r)
  float brz[8], bin4[4], bhn4[4];
#pragma unroll
  for (int jt = 0; jt < 8; ++jt) brz[jt] = bih[jt * 16 + r] + bhh[jt * 16 + r];
#pragma unroll
  for (int jt = 0; jt < 4; ++jt) {
    bin4[jt] = bih[128 + jt * 16 + r];
    bhn4[jt] = bhh[128 + jt * 16 + r];
  }

  const int gph = blockIdx.x * 4 + wv;  // graph id == wave id
  {
    // stage this graph's 16x16 walk ids, transposed to ids[t*16 + w]
    const int* wp = walks + gph * 256;
    int4 v = *(const int4*)(wp + lane * 4);
    int vals[4] = {v.x, v.y, v.z, v.w};
#pragma unroll
    for (int i = 0; i < 4; ++i) {
      int m = lane * 4 + i;  // m = w*16 + t
      ids[wv][(m & 15) * 16 + (m >> 4)] = vals[i];
    }
  }

  // zero h buffer (h0 = 0)
  for (int i = lane; i < 16 * 64; i += 64) h_lds[wv][i] = (_Float16)0.f;

  __syncthreads();

  f32x4 h[4];
#pragma unroll
  for (int jt = 0; jt < 4; ++jt) h[jt] = (f32x4){0.f, 0.f, 0.f, 0.f};

  char* hbase = (char*)&h_lds[wv][0];
  const int swz = (r & 7) << 4;  // XOR swizzle on 16B-granule bits 4..6

  for (int t = 0; t < 16; ++t) {
    // gather A_x fragments: row i = walk (lane&15), k = hidden of x_enc
    int nid = ids[wv][t * 16 + r];
    const _Float16* xp = xenc + (size_t)nid * 64 + g * 8;
    half8 Ax0 = *(const half8*)xp;
    half8 Ax1 = *(const half8*)(xp + 32);

    // A_h fragments from swizzled LDS (row = walk r, col-granule = kt*4+g)
    half8 Ah0 = *(const half8*)(hbase + ((r * 128 + g * 16) ^ swz));
    half8 Ah1 = *(const half8*)(hbase + ((r * 128 + 64 + g * 16) ^ swz));

    // init accumulators with biases (C-input of MFMA)
    f32x4 aRZ[8], aIN[4], aHN[4];
#pragma unroll
    for (int jt = 0; jt < 8; ++jt) aRZ[jt] = (f32x4){brz[jt], brz[jt], brz[jt], brz[jt]};
#pragma unroll
    for (int jt = 0; jt < 4; ++jt) {
      aIN[jt] = (f32x4){bin4[jt], bin4[jt], bin4[jt], bin4[jt]};
      aHN[jt] = (f32x4){bhn4[jt], bhn4[jt], bhn4[jt], bhn4[jt]};
    }

    // gh = h @ W_hh^T  (B from registers) — runs while A_x loads are in flight
#pragma unroll
    for (int jt = 0; jt < 8; ++jt) {
      aRZ[jt] = MFMA_F16(Ah0, Bhh[jt][0], aRZ[jt]);
      aRZ[jt] = MFMA_F16(Ah1, Bhh[jt][1], aRZ[jt]);
    }
#pragma unroll
    for (int jt = 0; jt < 4; ++jt) {
      aHN[jt] = MFMA_F16(Ah0, Bhh[8 + jt][0], aHN[jt]);
      aHN[jt] = MFMA_F16(Ah1, Bhh[8 + jt][1], aHN[jt]);
    }

    // gi = xt @ W_ih^T  (B frags from LDS)
#pragma unroll
    for (int jt = 0; jt < 8; ++jt) {
      half8 b0 = *(const half8*)&wih_lds[((jt * 2 + 0) * 64 + lane) * 8];
      half8 b1 = *(const half8*)&wih_lds[((jt * 2 + 1) * 64 + lane) * 8];
      aRZ[jt] = MFMA_F16(Ax0, b0, aRZ[jt]);
      aRZ[jt] = MFMA_F16(Ax1, b1, aRZ[jt]);
    }
#pragma unroll
    for (int jt = 0; jt < 4; ++jt) {
      half8 b0 = *(const half8*)&wih_lds[(((8 + jt) * 2 + 0) * 64 + lane) * 8];
      half8 b1 = *(const half8*)&wih_lds[(((8 + jt) * 2 + 1) * 64 + lane) * 8];
      aIN[jt] = MFMA_F16(Ax0, b0, aIN[jt]);
      aIN[jt] = MFMA_F16(Ax1, b1, aIN[jt]);
    }

    // gates: r = sig(i_r+h_r), z = sig(i_z+h_z), n = tanh(i_n + r*h_n)
#pragma unroll
    for (int jt = 0; jt < 4; ++jt)
#pragma unroll
      for (int rr = 0; rr < 4; ++rr) {
        float pr = aRZ[jt][rr];
        float pz = aRZ[4 + jt][rr];
        float rg = 1.f / (1.f + __expf(-pr));
        float zg = 1.f / (1.f + __expf(-pz));
        float pn = aIN[jt][rr] + rg * aHN[jt][rr];
        pn = fminf(fmaxf(pn, -15.f), 15.f);
        float e2 = __expf(2.f * pn);
        float nn = (e2 - 1.f) / (e2 + 1.f);
        h[jt][rr] = (1.f - zg) * nn + zg * h[jt][rr];
      }

    // write h (fp16) back to swizzled LDS for next step's A-fragments
    if (t < 15) {
#pragma unroll
      for (int jt = 0; jt < 4; ++jt)
#pragma unroll
        for (int rr = 0; rr < 4; ++rr) {
          int row = g * 4 + rr;
          int byte = (row * 128 + (jt * 16 + r) * 2) ^ ((row & 7) << 4);
          *(_Float16*)(hbase + byte) = (_Float16)h[jt][rr];
        }
    }
  }

  // fused segment-mean: mean over the wave's 16 walks (rows), per column
#pragma unroll
  for (int jt = 0; jt < 4; ++jt) {
    float s = h[jt][0] + h[jt][1] + h[jt][2] + h[jt][3];
    s += __shfl_xor(s, 16);
    s += __shfl_xor(s, 32);
    if (g == 0) genc[gph * 64 + jt * 16 + r] = s * 0.0625f;
  }
}

// ---------------- Kernel 3: BN batch stats -> scale/shift ----------------
__global__ __launch_bounds__(256) void k_stats(const float* __restrict__ genc,
                                               const float* __restrict__ gamma,
                                               const float* __restrict__ beta,
                                               float* __restrict__ ss) {
  __shared__ float sum_s[4][64], sq_s[4][64];
  int j = threadIdx.x & 63, grp = threadIdx.x >> 6;
  float s = 0.f, q = 0.f;
  for (int rr = 0; rr < 256; ++rr) {
    float v = genc[(grp * 256 + rr) * 64 + j];
    s += v;
    q += v * v;
  }
  sum_s[grp][j] = s;
  sq_s[grp][j] = q;
  __syncthreads();
  if (grp == 0) {
    float S = sum_s[0][j] + sum_s[1][j] + sum_s[2][j] + sum_s[3][j];
    float Q = sq_s[0][j] + sq_s[1][j] + sq_s[2][j] + sq_s[3][j];
    float mean = S * (1.f / 1024.f);
    float var = Q * (1.f / 1024.f) - mean * mean;
    float rstd = rsqrtf(var + 1e-5f);
    float sc = gamma[j] * rstd;
    ss[j] = sc;
    ss[64 + j] = beta[j] - mean * sc;
  }
}

// ---------------- Kernel 4: BN apply + MLP + log_softmax ----------------
__global__ __launch_bounds__(64) void k_mlp(const float* __restrict__ genc,
                                            const float* __restrict__ ss,
                                            const float* __restrict__ W1,
                                            const float* __restrict__ b1,
                                            const float* __restrict__ W2,
                                            const float* __restrict__ b2,
                                            float* __restrict__ out) {
  __shared__ float w1[32 * 64], w2[10 * 32], bb1[32], bb2[10], sc[64], sh[64];
  const int tid = threadIdx.x;
  for (int i = tid; i < 32 * 64; i += 64) w1[i] = W1[i];
  for (int i = tid; i < 10 * 32; i += 64) w2[i] = W2[i];
  if (tid < 32) bb1[tid] = b1[tid];
  if (tid < 10) bb2[tid] = b2[tid];
  sc[tid] = ss[tid];
  sh[tid] = ss[64 + tid];
  __syncthreads();

  const int row = blockIdx.x * 64 + tid;
  float gn[64];
  const f32x4* gp = (const f32x4*)(genc + row * 64);
#pragma unroll
  for (int jq = 0; jq < 16; ++jq) {
    f32x4 v = gp[jq];
#pragma unroll
    for (int e = 0; e < 4; ++e) gn[jq * 4 + e] = v[e] * sc[jq * 4 + e] + sh[jq * 4 + e];
  }

  float h1[32];
#pragma unroll
  for (int i = 0; i < 32; ++i) {
    float a = bb1[i];
#pragma unroll
    for (int j = 0; j < 64; ++j) a += w1[i * 64 + j] * gn[j];
    h1[i] = fmaxf(a, 0.f);
  }

  float lg[10];
  float mx = -1e30f;
#pragma unroll
  for (int c = 0; c < 10; ++c) {
    float a = bb2[c];
#pragma unroll
    for (int i = 0; i < 32; ++i) a += w2[c * 32 + i] * h1[i];
    lg[c] = a;
    mx = fmaxf(mx, a);
  }
  float se = 0.f;
#pragma unroll
  for (int c = 0; c < 10; ++c) se += __expf(lg[c] - mx);
  float lse = mx + __logf(se);
#pragma unroll
  for (int c = 0; c < 10; ++c) out[row * 10 + c] = lg[c] - lse;
}

// ---------------- host launcher ----------------
extern "C" void kernel_launch(void* const* d_in, const int* in_sizes, int n_in,
                              void* d_out, int out_size, void* d_ws, size_t ws_size,
                              hipStream_t stream) {
  const float* x = (const float*)d_in[0];
  const int* walks = (const int*)d_in[1];
  /* d_in[2] walk_batch: structure is repeat(arange(1024),16) -> wave==graph */
  const float* Wenc = (const float*)d_in[3];
  const float* benc = (const float*)d_in[4];
  const float* Wih = (const float*)d_in[5];
  const float* Whh = (const float*)d_in[6];
  const float* bih = (const float*)d_in[7];
  const float* bhh = (const float*)d_in[8];
  const float* gamma = (const float*)d_in[9];
  const float* beta = (const float*)d_in[10];
  const float* W1 = (const float*)d_in[11];
  const float* b1 = (const float*)d_in[12];
  const float* W2 = (const float*)d_in[13];
  const float* b2 = (const float*)d_in[14];
  float* out = (float*)d_out;

  char* ws = (char*)d_ws;
  _Float16* xenc = (_Float16*)ws;                    // 200000*64*2 = 25,600,000 B
  float* genc = (float*)(ws + 25600000);             // 1024*64*4   =    262,144 B
  float* ss = (float*)(ws + 25600000 + 262144);      // 128*4 B

  k_enc<<<dim3(3125), dim3(256), 0, stream>>>(x, Wenc, benc, xenc);
  k_gru<<<dim3(256), dim3(256), 0, stream>>>(xenc, walks, Wih, Whh, bih, bhh, genc);
  k_stats<<<dim3(1), dim3(256), 0, stream>>>(genc, gamma, beta, ss);
  k_mlp<<<dim3(16), dim3(64), 0, stream>>>(genc, ss, W1, b1, W2, b2, out);
}

// Round 4
// 97.029 us; speedup vs baseline: 1.5216x; 1.5216x over previous
//
#include <hip/hip_runtime.h>

typedef _Float16 half8 __attribute__((ext_vector_type(8)));
typedef float f32x4 __attribute__((ext_vector_type(4)));

#define MFMA_F16(A, B, C) __builtin_amdgcn_mfma_f32_16x16x32_f16(A, B, C, 0, 0, 0)

#define NN 200000

// RNE float->fp16 x8 (v_cvt_f16_f32 is round-nearest-even; matches Round-1 verified numerics)
__device__ __forceinline__ half8 cvt8(const float* p) {
  half8 a;
#pragma unroll
  for (int e = 0; e < 8; ++e) a[e] = (_Float16)p[e];
  return a;
}

// ---------------- Kernel 1: encoder  x_enc = fp16(x @ Wenc^T + benc) ----------------
// 256 rows/block (64/wave, 4 M-tiles), Wenc staged once per block in LDS.
__global__ __launch_bounds__(256) void k_enc(const float* __restrict__ x,
                                             const float* __restrict__ Wenc,
                                             const float* __restrict__ benc,
                                             _Float16* __restrict__ xenc) {
  __shared__ _Float16 wlds[16 * 64 * 8];  // frag-packed fp16 Wenc, 16 KB

  const int tid = threadIdx.x;
  const int lane = tid & 63, wv = tid >> 6;
  const int r = lane & 15, g = lane >> 4;

  // stage Wenc -> frag-packed fp16 LDS (coalesced global reads)
  for (int idx = tid; idx < 64 * 128; idx += 256) {
    int j = idx >> 7, k = idx & 127;
    int tile = (j >> 4) * 4 + (k >> 5);
    int ln = ((k >> 3) & 3) * 16 + (j & 15);
    wlds[(tile * 64 + ln) * 8 + (k & 7)] = (_Float16)Wenc[idx];
  }
  __syncthreads();

  // B fragments: 16 half8 = 64 VGPR, reused for 4 M-tiles
  half8 B[4][4];
#pragma unroll
  for (int jt = 0; jt < 4; ++jt)
#pragma unroll
    for (int kt = 0; kt < 4; ++kt)
      B[jt][kt] = *(const half8*)&wlds[((jt * 4 + kt) * 64 + lane) * 8];

  float bb[4];
#pragma unroll
  for (int jt = 0; jt < 4; ++jt) bb[jt] = benc[jt * 16 + r];

  const int base = blockIdx.x * 256 + wv * 64;

#pragma unroll
  for (int mt = 0; mt < 4; ++mt) {
    int arow = base + mt * 16 + r;
    if (arow >= NN) arow = NN - 1;  // clamp loads; stores guarded below

    f32x4 acc[4];
#pragma unroll
    for (int jt = 0; jt < 4; ++jt) acc[jt] = (f32x4){bb[jt], bb[jt], bb[jt], bb[jt]};

#pragma unroll
    for (int kt = 0; kt < 4; ++kt) {
      const float* p = x + (size_t)arow * 128 + kt * 32 + g * 8;
      half8 a = cvt8(p);
#pragma unroll
      for (int jt = 0; jt < 4; ++jt)
        acc[jt] = MFMA_F16(a, B[jt][kt], acc[jt]);
    }

    // C/D layout: col = lane&15, row = (lane>>4)*4 + reg
#pragma unroll
    for (int jt = 0; jt < 4; ++jt)
#pragma unroll
      for (int rr = 0; rr < 4; ++rr) {
        int row = base + mt * 16 + g * 4 + rr;
        if (row < NN) xenc[(size_t)row * 64 + jt * 16 + r] = (_Float16)acc[jt][rr];
      }
  }
}

// ---------------- Kernel 2: GRU over walks + per-graph mean pooling ----------------
// 1 wave = 1 graph = 16 walks. grid 256 x 256thr. All weights in registers.
__global__ __launch_bounds__(256, 1) void k_gru(const _Float16* __restrict__ xenc,
                                                const int* __restrict__ walks,
                                                const float* __restrict__ Wih,
                                                const float* __restrict__ Whh,
                                                const float* __restrict__ bih,
                                                const float* __restrict__ bhh,
                                                float* __restrict__ genc) {
  __shared__ _Float16 h_lds[4][16 * 64];  // per-wave h transpose buffer (8 KB)
  __shared__ int ids[4][256];             // per-wave walk node ids, transposed (4 KB)

  const int tid = threadIdx.x;
  const int lane = tid & 63, wv = tid >> 6;
  const int r = lane & 15, g = lane >> 4;

  // W_ih and W_hh fragments in registers (48 half8 = 192 VGPR), reused 16 steps
  half8 Bih[12][2], Bhh[12][2];
#pragma unroll
  for (int jt = 0; jt < 12; ++jt)
#pragma unroll
    for (int kt = 0; kt < 2; ++kt) {
      Bih[jt][kt] = cvt8(Wih + (jt * 16 + r) * 64 + kt * 32 + g * 8);
      Bhh[jt][kt] = cvt8(Whh + (jt * 16 + r) * 64 + kt * 32 + g * 8);
    }

  // per-lane biases (indexed by output col = jt*16 + r)
  float brz[8], bin4[4], bhn4[4];
#pragma unroll
  for (int jt = 0; jt < 8; ++jt) brz[jt] = bih[jt * 16 + r] + bhh[jt * 16 + r];
#pragma unroll
  for (int jt = 0; jt < 4; ++jt) {
    bin4[jt] = bih[128 + jt * 16 + r];
    bhn4[jt] = bhh[128 + jt * 16 + r];
  }

  const int gph = blockIdx.x * 4 + wv;  // graph id == wave id
  {
    const int* wp = walks + gph * 256;
    int4 v = *(const int4*)(wp + lane * 4);
    int vals[4] = {v.x, v.y, v.z, v.w};
#pragma unroll
    for (int i = 0; i < 4; ++i) {
      int m = lane * 4 + i;  // m = w*16 + t
      ids[wv][(m & 15) * 16 + (m >> 4)] = vals[i];
    }
  }

  for (int i = lane; i < 16 * 64; i += 64) h_lds[wv][i] = (_Float16)0.f;
  // no __syncthreads needed: all LDS traffic is wave-private

  f32x4 h[4];
#pragma unroll
  for (int jt = 0; jt < 4; ++jt) h[jt] = (f32x4){0.f, 0.f, 0.f, 0.f};

  char* hbase = (char*)&h_lds[wv][0];
  const int swz = (r & 7) << 4;

  // prefetch step 0 gather
  int nid0 = ids[wv][r];
  const _Float16* xp0 = xenc + (size_t)nid0 * 64 + g * 8;
  half8 Ax0 = *(const half8*)xp0;
  half8 Ax1 = *(const half8*)(xp0 + 32);

#pragma unroll 2
  for (int t = 0; t < 16; ++t) {
    // prefetch step t+1 gather (ids known upfront; hides L2/L3 latency)
    int tn = (t + 1) & 15;
    int nid = ids[wv][tn * 16 + r];
    const _Float16* xp = xenc + (size_t)nid * 64 + g * 8;
    half8 Nx0 = *(const half8*)xp;
    half8 Nx1 = *(const half8*)(xp + 32);

    // A_h fragments from swizzled LDS (row = walk r)
    half8 Ah0 = *(const half8*)(hbase + ((r * 128 + g * 16) ^ swz));
    half8 Ah1 = *(const half8*)(hbase + ((r * 128 + 64 + g * 16) ^ swz));

    f32x4 aRZ[8], aIN[4], aHN[4];
#pragma unroll
    for (int jt = 0; jt < 8; ++jt) aRZ[jt] = (f32x4){brz[jt], brz[jt], brz[jt], brz[jt]};
#pragma unroll
    for (int jt = 0; jt < 4; ++jt) {
      aIN[jt] = (f32x4){bin4[jt], bin4[jt], bin4[jt], bin4[jt]};
      aHN[jt] = (f32x4){bhn4[jt], bhn4[jt], bhn4[jt], bhn4[jt]};
    }

    // gi = xt @ W_ih^T first (Ax ready from prefetch)
#pragma unroll
    for (int jt = 0; jt < 8; ++jt) {
      aRZ[jt] = MFMA_F16(Ax0, Bih[jt][0], aRZ[jt]);
      aRZ[jt] = MFMA_F16(Ax1, Bih[jt][1], aRZ[jt]);
    }
#pragma unroll
    for (int jt = 0; jt < 4; ++jt) {
      aIN[jt] = MFMA_F16(Ax0, Bih[8 + jt][0], aIN[jt]);
      aIN[jt] = MFMA_F16(Ax1, Bih[8 + jt][1], aIN[jt]);
    }

    // gh = h @ W_hh^T
#pragma unroll
    for (int jt = 0; jt < 8; ++jt) {
      aRZ[jt] = MFMA_F16(Ah0, Bhh[jt][0], aRZ[jt]);
      aRZ[jt] = MFMA_F16(Ah1, Bhh[jt][1], aRZ[jt]);
    }
#pragma unroll
    for (int jt = 0; jt < 4; ++jt) {
      aHN[jt] = MFMA_F16(Ah0, Bhh[8 + jt][0], aHN[jt]);
      aHN[jt] = MFMA_F16(Ah1, Bhh[8 + jt][1], aHN[jt]);
    }

    // gates (division-free: raw v_rcp; tanh = 1 - 2*rcp(e2+1), saturates correctly)
#pragma unroll
    for (int jt = 0; jt < 4; ++jt)
#pragma unroll
      for (int rr = 0; rr < 4; ++rr) {
        float pr = aRZ[jt][rr];
        float pz = aRZ[4 + jt][rr];
        float rg = __builtin_amdgcn_rcpf(1.f + __expf(-pr));
        float zg = __builtin_amdgcn_rcpf(1.f + __expf(-pz));
        float pn = aIN[jt][rr] + rg * aHN[jt][rr];
        float e2 = __expf(2.f * pn);
        float nn = 1.f - 2.f * __builtin_amdgcn_rcpf(e2 + 1.f);
        h[jt][rr] = (1.f - zg) * nn + zg * h[jt][rr];
      }

    // write h (fp16) back to swizzled LDS for next step's A-fragments
    if (t < 15) {
#pragma unroll
      for (int jt = 0; jt < 4; ++jt)
#pragma unroll
        for (int rr = 0; rr < 4; ++rr) {
          int row = g * 4 + rr;
          int byte = (row * 128 + (jt * 16 + r) * 2) ^ ((row & 7) << 4);
          *(_Float16*)(hbase + byte) = (_Float16)h[jt][rr];
        }
    }

    Ax0 = Nx0;
    Ax1 = Nx1;
  }

  // fused segment-mean over the wave's 16 walks
#pragma unroll
  for (int jt = 0; jt < 4; ++jt) {
    float s = h[jt][0] + h[jt][1] + h[jt][2] + h[jt][3];
    s += __shfl_xor(s, 16);
    s += __shfl_xor(s, 32);
    if (g == 0) genc[gph * 64 + jt * 16 + r] = s * 0.0625f;
  }
}

// ---------------- Kernel 3: BN batch stats -> scale/shift ----------------
__global__ __launch_bounds__(1024) void k_stats(const float* __restrict__ genc,
                                                const float* __restrict__ gamma,
                                                const float* __restrict__ beta,
                                                float* __restrict__ ss) {
  __shared__ float sum_s[16][64], sq_s[16][64];
  int j = threadIdx.x & 63, grp = threadIdx.x >> 6;
  float s = 0.f, q = 0.f;
#pragma unroll 4
  for (int rr = 0; rr < 64; ++rr) {
    float v = genc[(grp * 64 + rr) * 64 + j];
    s += v;
    q += v * v;
  }
  sum_s[grp][j] = s;
  sq_s[grp][j] = q;
  __syncthreads();
  if (grp == 0) {
    float S = 0.f, Q = 0.f;
#pragma unroll
    for (int k = 0; k < 16; ++k) {
      S += sum_s[k][j];
      Q += sq_s[k][j];
    }
    float mean = S * (1.f / 1024.f);
    float var = Q * (1.f / 1024.f) - mean * mean;
    float rstd = rsqrtf(var + 1e-5f);
    float sc = gamma[j] * rstd;
    ss[j] = sc;
    ss[64 + j] = beta[j] - mean * sc;
  }
}

// ---------------- Kernel 4: BN apply + MLP + log_softmax ----------------
__global__ __launch_bounds__(256, 1) void k_mlp(const float* __restrict__ genc,
                                                const float* __restrict__ ss,
                                                const float* __restrict__ W1,
                                                const float* __restrict__ b1,
                                                const float* __restrict__ W2,
                                                const float* __restrict__ b2,
                                                float* __restrict__ out) {
  __shared__ float w1[32 * 64], w2[10 * 32], bb1[32], bb2[10], sc[64], sh[64];
  const int tid = threadIdx.x;
  for (int i = tid; i < 32 * 64; i += 256) w1[i] = W1[i];
  for (int i = tid; i < 10 * 32; i += 256) w2[i] = W2[i];  // FIX: loop, 320 > 256 threads
  if (tid < 32) bb1[tid] = b1[tid];
  if (tid >= 32 && tid < 42) bb2[tid - 32] = b2[tid - 32];
  if (tid >= 64 && tid < 128) sc[tid - 64] = ss[tid - 64];
  if (tid >= 128 && tid < 192) sh[tid - 128] = ss[64 + tid - 128];
  __syncthreads();

  const int row = blockIdx.x * 256 + tid;
  float gn[64];
  const f32x4* gp = (const f32x4*)(genc + row * 64);
#pragma unroll
  for (int jq = 0; jq < 16; ++jq) {
    f32x4 v = gp[jq];
#pragma unroll
    for (int e = 0; e < 4; ++e) gn[jq * 4 + e] = v[e] * sc[jq * 4 + e] + sh[jq * 4 + e];
  }

  float h1[32];
#pragma unroll
  for (int i = 0; i < 32; ++i) {
    float a = bb1[i];
#pragma unroll
    for (int j = 0; j < 64; ++j) a += w1[i * 64 + j] * gn[j];
    h1[i] = fmaxf(a, 0.f);
  }

  float lg[10];
  float mx = -1e30f;
#pragma unroll
  for (int c = 0; c < 10; ++c) {
    float a = bb2[c];
#pragma unroll
    for (int i = 0; i < 32; ++i) a += w2[c * 32 + i] * h1[i];
    lg[c] = a;
    mx = fmaxf(mx, a);
  }
  float se = 0.f;
#pragma unroll
  for (int c = 0; c < 10; ++c) se += __expf(lg[c] - mx);
  float lse = mx + __logf(se);
#pragma unroll
  for (int c = 0; c < 10; ++c) out[row * 10 + c] = lg[c] - lse;
}

// ---------------- host launcher ----------------
extern "C" void kernel_launch(void* const* d_in, const int* in_sizes, int n_in,
                              void* d_out, int out_size, void* d_ws, size_t ws_size,
                              hipStream_t stream) {
  const float* x = (const float*)d_in[0];
  const int* walks = (const int*)d_in[1];
  /* d_in[2] walk_batch: repeat(arange(1024),16) -> wave==graph */
  const float* Wenc = (const float*)d_in[3];
  const float* benc = (const float*)d_in[4];
  const float* Wih = (const float*)d_in[5];
  const float* Whh = (const float*)d_in[6];
  const float* bih = (const float*)d_in[7];
  const float* bhh = (const float*)d_in[8];
  const float* gamma = (const float*)d_in[9];
  const float* beta = (const float*)d_in[10];
  const float* W1 = (const float*)d_in[11];
  const float* b1 = (const float*)d_in[12];
  const float* W2 = (const float*)d_in[13];
  const float* b2 = (const float*)d_in[14];
  float* out = (float*)d_out;

  char* ws = (char*)d_ws;
  _Float16* xenc = (_Float16*)ws;                 // 25,600,000 B
  float* genc = (float*)(ws + 25600000);          // 262,144 B
  float* ss = (float*)(ws + 25600000 + 262144);   // 512 B

  k_enc<<<dim3(782), dim3(256), 0, stream>>>(x, Wenc, benc, xenc);
  k_gru<<<dim3(256), dim3(256), 0, stream>>>(xenc, walks, Wih, Whh, bih, bhh, genc);
  k_stats<<<dim3(1), dim3(1024), 0, stream>>>(genc, gamma, beta, ss);
  k_mlp<<<dim3(4), dim3(256), 0, stream>>>(genc, ss, W1, b1, W2, b2, out);
}